// Round 16
// baseline (55.422 us; speedup 1.0000x reference)
//
#include <hip/hip_runtime.h>

// KernelExpansion: out[m] = sum_n sigma^2 * w[n] * exp(-0.5*||s_n - x_m||^2 / l^2)
// Round-16: packed-polynomial exp2 (bypass the trans unit).
//  r6-r15: eight structurally different kernels all pin at 33-37us across
//  occupancy 2.5-8 waves/SIMD, LDS/global operands, prefetch, sched_barrier ->
//  shared-pipe floor. Fit: v_exp_f32 ~32cyc/wave64 -> 27.3us trans floor +
//  adds/staging == the observed pin. Replace exp2 with full-rate packed VALU:
//   magic-const round (t=x+1.5*2^23), f=x-(t-C) in [-.5,.5], deg-5 Horner in
//   v_pk_fma_f32, scale=(t_bits+127)<<23 bitcast, final mul FUSED into the
//   p-accumulate (pk_fma(poly, scale, p)). ~12 wave-ops / 2 elements.
//  Base structure = r15 (exact residency: 1024 blocks x 512 thr = 8192 waves
//  = device capacity; s-chunk LDS-staged fragment order; B-frags in-register;
//  K-pad constant folding: acc IS the exp2 argument).
// C/D layout (verified r4 pass): acc[i] -> n-row q*4+i, m-col r.

#define LOG2E_F 1.4426950408889634f

typedef __attribute__((ext_vector_type(8))) short bf16x8;   // 8 bf16 = 4 VGPRs
typedef __attribute__((ext_vector_type(4))) float f32x4;
typedef float v2f_ __attribute__((ext_vector_type(2)));
typedef unsigned int u32x2 __attribute__((ext_vector_type(2)));

constexpr int D      = 24;
constexpr int TILES  = 4;    // 16-col tiles per wave -> 64 m per wave
constexpr int WB     = 8;    // waves per block
constexpr int TPB    = 64 * WB;  // 512
constexpr int NSPLIT = 32;   // n-chunks of 256 rows
constexpr int CT     = 16;   // tiles per chunk (256 rows)

__device__ inline unsigned short f32_to_bf16_rne(float f) {
    unsigned u = __builtin_bit_cast(unsigned, f);
    u += 0x7fffu + ((u >> 16) & 1u);
    return (unsigned short)(u >> 16);
}
__device__ inline float bf16_to_f32(unsigned short h) {
    unsigned u = ((unsigned)h) << 16;
    return __builtin_bit_cast(float, u);
}

constexpr unsigned short BF16_ONE = 0x3F80;

// exp2(x) for x <= ~0 via full-rate packed VALU; accumulates p += exp2(x).
// Magic-constant round-to-nearest, deg-5 Taylor on [-0.5,0.5] (rel err 2.4e-6),
// scale constructed as (t_bits+127)<<23.  ~12 wave-ops per 2 elements.
__device__ inline void exp2_fma_acc(v2f_ x, v2f_& acc) {
    const v2f_ Cv   = {12582912.f, 12582912.f};   // 1.5 * 2^23
    const v2f_ cmin = {-126.f, -126.f};
    v2f_ xc = __builtin_elementwise_max(x, cmin);
    v2f_ t  = xc + Cv;
    v2f_ nf = t - Cv;
    v2f_ f  = xc - nf;
    u32x2 tb = __builtin_bit_cast(u32x2, t);
    u32x2 sb = (tb + 127u) << 23;                 // (n+127)<<23, low bits clean
    v2f_ scale = __builtin_bit_cast(v2f_, sb);
    v2f_ r   = {0.0013333558146428441f, 0.0013333558146428441f};  // c5
    r = __builtin_elementwise_fma(r, f, (v2f_){0.009618129107628477f, 0.009618129107628477f});
    r = __builtin_elementwise_fma(r, f, (v2f_){0.05550410866482158f, 0.05550410866482158f});
    r = __builtin_elementwise_fma(r, f, (v2f_){0.2402265069591007f, 0.2402265069591007f});
    r = __builtin_elementwise_fma(r, f, (v2f_){0.6931471805599453f, 0.6931471805599453f});
    r = __builtin_elementwise_fma(r, f, (v2f_){1.0f, 1.0f});
    acc = __builtin_elementwise_fma(r, scale, acc);
}

__global__ __launch_bounds__(TPB, 8) void ke_fused(
    const float* __restrict__ x, const float* __restrict__ s,
    const float* __restrict__ wts,
    const float* __restrict__ sigma_p, const float* __restrict__ length_p,
    float* __restrict__ out, int M, int N, int MGRP) {
    __shared__ __align__(16) unsigned short sm[16384];  // 32KB: hi [0,8192) lo [8192,16384)
    int t    = threadIdx.x;
    int lane = t & 63;
    int wv   = t >> 6;
    int mg   = blockIdx.x % MGRP;
    int ns   = blockIdx.x / MGRP;
    int r    = lane & 15;
    int q    = lane >> 4;

    float l    = length_p[0];
    float c2   = -0.5f * LOG2E_F / (l * l);
    float m2c2 = -2.f * c2;
    float sg   = sigma_p[0];

    // ---- stage this block's 256 s-rows (n-chunk) into LDS, fragment order.
    if (t < 256) {
        int row = ns * 256 + t;
        const float* sr = s + (size_t)row * D;
        float v[24];
        float ssq = 0.f;
#pragma unroll
        for (int i = 0; i < 6; ++i) {
            float4 f = reinterpret_cast<const float4*>(sr)[i];
            v[4*i+0] = f.x; v[4*i+1] = f.y; v[4*i+2] = f.z; v[4*i+3] = f.w;
        }
#pragma unroll
        for (int d = 0; d < 24; ++d) ssq = fmaf(v[d], v[d], ssq);
        float lwt = __log2f(sg * sg * wts[row]) + c2 * ssq;
        lwt = fmaxf(lwt, -16000.f);              // w -> 0: finite, exp2 -> 0
        unsigned short hi[32], lo[32];
#pragma unroll
        for (int d = 0; d < 24; ++d) {
            float vs = m2c2 * v[d];
            unsigned short h = f32_to_bf16_rne(vs);
            hi[d] = h;
            lo[d] = f32_to_bf16_rne(vs - bf16_to_f32(h));
        }
        unsigned short lhi = f32_to_bf16_rne(lwt);
        hi[24] = lhi; hi[25] = f32_to_bf16_rne(lwt - bf16_to_f32(lhi));
        hi[26] = BF16_ONE; hi[27] = BF16_ONE;
        hi[28] = 0; hi[29] = 0; hi[30] = 0; hi[31] = 0;
#pragma unroll
        for (int d = 24; d < 32; ++d) lo[d] = 0;
        int sb = (t >> 4) * 512 + (t & 15) * 8;  // fragment-order slot base
#pragma unroll
        for (int q2 = 0; q2 < 4; ++q2) {
            bf16x8 vh, vl;
#pragma unroll
            for (int j2 = 0; j2 < 8; ++j2) { vh[j2] = (short)hi[q2*8+j2]; vl[j2] = (short)lo[q2*8+j2]; }
            *reinterpret_cast<bf16x8*>(sm + sb + q2 * 128) = vh;
            *reinterpret_cast<bf16x8*>(sm + 8192 + sb + q2 * 128) = vl;
        }
    }

    // ---- build B fragments (x) in-register from global (overlaps staging).
    int m0 = mg * (TILES * 16 * WB) + wv * (TILES * 16);
    bf16x8 bh[TILES], bl[TILES];
#pragma unroll
    for (int j = 0; j < TILES; ++j) {
        int row = m0 + j * 16 + r;
        int qc  = (q < 3) ? q : 2;               // clamped in-bounds load
        const float4* xp = reinterpret_cast<const float4*>(x + (size_t)row * D + qc * 8);
        float4 f0 = xp[0], f1 = xp[1];
        float v8[8] = {f0.x, f0.y, f0.z, f0.w, f1.x, f1.y, f1.z, f1.w};
        float live = (q < 3) ? 1.f : 0.f;
        float psq = 0.f;
#pragma unroll
        for (int e = 0; e < 8; ++e) psq = fmaf(v8[e], v8[e], psq);
        psq *= live;
        psq += __shfl_xor(psq, 16, 64);
        psq += __shfl_xor(psq, 32, 64);
        float cxv = c2 * psq;
        if (q < 3) {
#pragma unroll
            for (int e = 0; e < 8; ++e) {
                unsigned short h = f32_to_bf16_rne(v8[e]);
                bh[j][e] = (short)h;
                bl[j][e] = (short)f32_to_bf16_rne(v8[e] - bf16_to_f32(h));
            }
        } else {
            unsigned short chv = f32_to_bf16_rne(cxv);
            bh[j][0] = (short)BF16_ONE; bh[j][1] = (short)BF16_ONE;
            bh[j][2] = (short)chv;
            bh[j][3] = (short)f32_to_bf16_rne(cxv - bf16_to_f32(chv));
            bh[j][4] = 0; bh[j][5] = 0; bh[j][6] = 0; bh[j][7] = 0;
#pragma unroll
            for (int e = 0; e < 8; ++e) bl[j][e] = 0;
        }
    }
#pragma unroll
    for (int j = 0; j < TILES; ++j) { asm("" : "+v"(bh[j]), "+v"(bl[j])); }

    __syncthreads();

    // ---- main loop: 16 tiles from LDS; epilogue = packed-poly exp2.
    v2f_ p2[TILES] = {{0.f,0.f},{0.f,0.f},{0.f,0.f},{0.f,0.f}};
#pragma unroll 1
    for (int tt = 0; tt < CT; ++tt) {
        bf16x8 ah = *reinterpret_cast<const bf16x8*>(sm + ((size_t)tt * 64 + lane) * 8);
        bf16x8 al = *reinterpret_cast<const bf16x8*>(sm + 8192 + ((size_t)tt * 64 + lane) * 8);
#pragma unroll
        for (int j = 0; j < TILES; ++j) {
            f32x4 z = {0.f, 0.f, 0.f, 0.f};
            f32x4 acc = __builtin_amdgcn_mfma_f32_16x16x32_bf16(ah, bh[j], z, 0, 0, 0);
            acc = __builtin_amdgcn_mfma_f32_16x16x32_bf16(al, bh[j], acc, 0, 0, 0);
            acc = __builtin_amdgcn_mfma_f32_16x16x32_bf16(ah, bl[j], acc, 0, 0, 0);
            v2f_ x01 = {acc[0], acc[1]};
            v2f_ x23 = {acc[2], acc[3]};
            exp2_fma_acc(x01, p2[j]);
            exp2_fma_acc(x23, p2[j]);
        }
    }
    // reduce over the 4 q-quarters (column r fixed) and accumulate
#pragma unroll
    for (int j = 0; j < TILES; ++j) {
        float p = p2[j].x + p2[j].y;
        p += __shfl_xor(p, 16, 64);
        p += __shfl_xor(p, 32, 64);
        if (lane < 16) atomicAdd(&out[m0 + j * 16 + r], p);
    }
}

// ---- fallback: fp32 VALU kernel (no workspace needed)
constexpr int FTPB = 256;
constexpr int MPT  = 2;
constexpr int MBLK = FTPB * MPT;

__global__ __launch_bounds__(FTPB) void ke_plain(
    const float* __restrict__ x, const float* __restrict__ samples,
    const float* __restrict__ weights, const float* __restrict__ sigma_p,
    const float* __restrict__ length_p, float* __restrict__ out,
    int M, int N, int nsplit, int chunk) {
    int mb = blockIdx.x / nsplit;
    int ns = blockIdx.x - mb * nsplit;
    int t  = threadIdx.x;
    int m0 = mb * MBLK + t;
    int m1 = m0 + FTPB;
    int m0c = (m0 < M) ? m0 : 0;
    int m1c = (m1 < M) ? m1 : 0;

    v2f_ xaq[D / 2], xbq[D / 2];
    const v2f_* xp0 = reinterpret_cast<const v2f_*>(x + (size_t)m0c * D);
    const v2f_* xp1 = reinterpret_cast<const v2f_*>(x + (size_t)m1c * D);
#pragma unroll
    for (int qq = 0; qq < D / 2; ++qq) { xaq[qq] = xp0[qq]; xbq[qq] = xp1[qq]; }
#pragma unroll
    for (int qq = 0; qq < D / 2; ++qq) { asm("" : "+v"(xaq[qq])); asm("" : "+v"(xbq[qq])); }

    float l   = length_p[0];
    float c   = -0.5f * LOG2E_F / (l * l);
    float m2c = -2.f * c;
    float sg  = sigma_p[0];
    float sg2 = sg * sg;

    v2f_ qa = {0.f, 0.f}, qb = {0.f, 0.f};
#pragma unroll
    for (int qq = 0; qq < D / 2; ++qq) {
        qa = __builtin_elementwise_fma(xaq[qq], xaq[qq], qa);
        qb = __builtin_elementwise_fma(xbq[qq], xbq[qq], qb);
    }
    float cxa = c * (qa.x + qa.y);
    float cxb = c * (qb.x + qb.y);

    float acc0 = 0.f, acc1 = 0.f;
    int n0 = ns * chunk;
    int n1 = n0 + chunk;
    if (n1 > N) n1 = N;
#pragma unroll 2
    for (int n = n0; n < n1; ++n) {
        const v2f_* s2 = reinterpret_cast<const v2f_*>(samples + (size_t)n * D);
        v2f_ da = {0.f, 0.f}, db = {0.f, 0.f}, sq = {0.f, 0.f};
#pragma unroll
        for (int qq = 0; qq < D / 2; ++qq) {
            v2f_ sv = s2[qq];
            sq = __builtin_elementwise_fma(sv, sv, sq);
            da = __builtin_elementwise_fma(sv, xaq[qq], da);
            db = __builtin_elementwise_fma(sv, xbq[qq], db);
        }
        float cn = c * (sq.x + sq.y);
        float wn = sg2 * weights[n];
        float e0 = fmaf(m2c, da.x + da.y, cn);
        float e1 = fmaf(m2c, db.x + db.y, cn);
        acc0 = fmaf(wn, __builtin_amdgcn_exp2f(e0), acc0);
        acc1 = fmaf(wn, __builtin_amdgcn_exp2f(e1), acc1);
    }
    if (m0 < M) atomicAdd(&out[m0], acc0 * __builtin_amdgcn_exp2f(cxa));
    if (m1 < M) atomicAdd(&out[m1], acc1 * __builtin_amdgcn_exp2f(cxb));
}

extern "C" void kernel_launch(void* const* d_in, const int* in_sizes, int n_in,
                              void* d_out, int out_size, void* d_ws, size_t ws_size,
                              hipStream_t stream) {
    const float* x       = (const float*)d_in[0];
    const float* samples = (const float*)d_in[1];
    const float* weights = (const float*)d_in[2];
    const float* sigma_p = (const float*)d_in[3];
    const float* length_p= (const float*)d_in[4];
    float* out = (float*)d_out;

    int M = in_sizes[0] / D;
    int N = in_sizes[1] / D;

    hipMemsetAsync(out, 0, (size_t)out_size * sizeof(float), stream);

    int MSPAN = TILES * 16 * WB;                 // 512 m per block
    bool fused_ok = (M % MSPAN) == 0 && (N == NSPLIT * CT * 16) && out_size >= M;

    if (fused_ok) {
        int MGRP   = M / MSPAN;                  // 32
        int blocks = MGRP * NSPLIT;              // 1024 = exact device capacity
        ke_fused<<<dim3(blocks), dim3(TPB), 0, stream>>>(
            x, samples, weights, sigma_p, length_p, out, M, N, MGRP);
    } else {
        int mbcnt  = (M + MBLK - 1) / MBLK;
        int nsplit = 2048 / (mbcnt > 0 ? mbcnt : 1);
        if (nsplit < 1) nsplit = 1;
        if (nsplit > N) nsplit = N;
        int chunk = (N + nsplit - 1) / nsplit;
        ke_plain<<<dim3(mbcnt * nsplit), dim3(FTPB), 0, stream>>>(
            x, samples, weights, sigma_p, length_p, out, M, N, nsplit, chunk);
    }
}

// Round 19
// 35.159 us; speedup vs baseline: 1.5763x; 1.5763x over previous
//
#include <hip/hip_runtime.h>

// KernelExpansion: out[m] = sum_n sigma^2 * w[n] * exp(-0.5*||s_n - x_m||^2 / l^2)
// Round-19 (= r17/r18 resubmit after repeated infra failures): wave de-phasing.
//  r16 lesson: poly-exp2 regressed 35->55us; added VALU work showed up 1:1 in
//  time -> MFMA and VALU/trans behave serialized per SIMD. Model: all 8 waves
//  are barrier-released together and walk IDENTICAL tile sequences -> lockstep
//  phases (all-MFMA then all-exp), each pipe idle half the time. Serial-sum
//  (192 MFMA-cyc + ~128-256 trans-cyc + 24 add-cyc per tile) matches the
//  33-35us pin. Fix: each wave starts its tile walk at offset 2*wv
//  (tt = (tt0 + 2*wv) & 15) -> waves hit MFMA/exp phases at different times,
//  letting matrix and trans pipes overlap ACROSS waves. Same work, same LDS.
//  If neutral: pipes are per-wave HW-serialized -> 33-35us is this
//  formulation's roofline.
// C/D layout (verified r4 pass): acc[i] -> n-row q*4+i, m-col r.

#define LOG2E_F 1.4426950408889634f

typedef __attribute__((ext_vector_type(8))) short bf16x8;   // 8 bf16 = 4 VGPRs
typedef __attribute__((ext_vector_type(4))) float f32x4;
typedef float v2f_ __attribute__((ext_vector_type(2)));

constexpr int D      = 24;
constexpr int TILES  = 4;    // 16-col tiles per wave -> 64 m per wave
constexpr int WB     = 8;    // waves per block
constexpr int TPB    = 64 * WB;  // 512
constexpr int NSPLIT = 32;   // n-chunks of 256 rows
constexpr int CT     = 16;   // tiles per chunk (256 rows)

__device__ inline unsigned short f32_to_bf16_rne(float f) {
    unsigned u = __builtin_bit_cast(unsigned, f);
    u += 0x7fffu + ((u >> 16) & 1u);
    return (unsigned short)(u >> 16);
}
__device__ inline float bf16_to_f32(unsigned short h) {
    unsigned u = ((unsigned)h) << 16;
    return __builtin_bit_cast(float, u);
}

constexpr unsigned short BF16_ONE = 0x3F80;

__global__ __launch_bounds__(TPB, 8) void ke_fused(
    const float* __restrict__ x, const float* __restrict__ s,
    const float* __restrict__ wts,
    const float* __restrict__ sigma_p, const float* __restrict__ length_p,
    float* __restrict__ out, int M, int N, int MGRP) {
    __shared__ __align__(16) unsigned short sm[16384];  // 32KB: hi [0,8192) lo [8192,16384)
    int t    = threadIdx.x;
    int lane = t & 63;
    int wv   = t >> 6;
    int mg   = blockIdx.x % MGRP;
    int ns   = blockIdx.x / MGRP;
    int r    = lane & 15;
    int q    = lane >> 4;

    float l    = length_p[0];
    float c2   = -0.5f * LOG2E_F / (l * l);
    float m2c2 = -2.f * c2;
    float sg   = sigma_p[0];

    // ---- stage this block's 256 s-rows (n-chunk) into LDS, fragment order.
    if (t < 256) {
        int row = ns * 256 + t;
        const float* sr = s + (size_t)row * D;
        float v[24];
        float ssq = 0.f;
#pragma unroll
        for (int i = 0; i < 6; ++i) {
            float4 f = reinterpret_cast<const float4*>(sr)[i];
            v[4*i+0] = f.x; v[4*i+1] = f.y; v[4*i+2] = f.z; v[4*i+3] = f.w;
        }
#pragma unroll
        for (int d = 0; d < 24; ++d) ssq = fmaf(v[d], v[d], ssq);
        float lwt = __log2f(sg * sg * wts[row]) + c2 * ssq;
        lwt = fmaxf(lwt, -20000.f);              // w -> 0: finite, exp2 -> 0
        unsigned short hi[32], lo[32];
#pragma unroll
        for (int d = 0; d < 24; ++d) {
            float vs = m2c2 * v[d];
            unsigned short h = f32_to_bf16_rne(vs);
            hi[d] = h;
            lo[d] = f32_to_bf16_rne(vs - bf16_to_f32(h));
        }
        unsigned short lhi = f32_to_bf16_rne(lwt);
        hi[24] = lhi; hi[25] = f32_to_bf16_rne(lwt - bf16_to_f32(lhi));
        hi[26] = BF16_ONE; hi[27] = BF16_ONE;
        hi[28] = 0; hi[29] = 0; hi[30] = 0; hi[31] = 0;
#pragma unroll
        for (int d = 24; d < 32; ++d) lo[d] = 0;
        int sb = (t >> 4) * 512 + (t & 15) * 8;  // fragment-order slot base
#pragma unroll
        for (int q2 = 0; q2 < 4; ++q2) {
            bf16x8 vh, vl;
#pragma unroll
            for (int j2 = 0; j2 < 8; ++j2) { vh[j2] = (short)hi[q2*8+j2]; vl[j2] = (short)lo[q2*8+j2]; }
            *reinterpret_cast<bf16x8*>(sm + sb + q2 * 128) = vh;
            *reinterpret_cast<bf16x8*>(sm + 8192 + sb + q2 * 128) = vl;
        }
    }

    // ---- build B fragments (x) in-register from global (overlaps staging).
    int m0 = mg * (TILES * 16 * WB) + wv * (TILES * 16);
    bf16x8 bh[TILES], bl[TILES];
#pragma unroll
    for (int j = 0; j < TILES; ++j) {
        int row = m0 + j * 16 + r;
        int qc  = (q < 3) ? q : 2;               // clamped in-bounds load
        const float4* xp = reinterpret_cast<const float4*>(x + (size_t)row * D + qc * 8);
        float4 f0 = xp[0], f1 = xp[1];
        float v8[8] = {f0.x, f0.y, f0.z, f0.w, f1.x, f1.y, f1.z, f1.w};
        float live = (q < 3) ? 1.f : 0.f;
        float psq = 0.f;
#pragma unroll
        for (int e = 0; e < 8; ++e) psq = fmaf(v8[e], v8[e], psq);
        psq *= live;
        psq += __shfl_xor(psq, 16, 64);
        psq += __shfl_xor(psq, 32, 64);
        float cxv = c2 * psq;
        if (q < 3) {
#pragma unroll
            for (int e = 0; e < 8; ++e) {
                unsigned short h = f32_to_bf16_rne(v8[e]);
                bh[j][e] = (short)h;
                bl[j][e] = (short)f32_to_bf16_rne(v8[e] - bf16_to_f32(h));
            }
        } else {
            unsigned short chv = f32_to_bf16_rne(cxv);
            bh[j][0] = (short)BF16_ONE; bh[j][1] = (short)BF16_ONE;
            bh[j][2] = (short)chv;
            bh[j][3] = (short)f32_to_bf16_rne(cxv - bf16_to_f32(chv));
            bh[j][4] = 0; bh[j][5] = 0; bh[j][6] = 0; bh[j][7] = 0;
#pragma unroll
            for (int e = 0; e < 8; ++e) bl[j][e] = 0;
        }
    }
#pragma unroll
    for (int j = 0; j < TILES; ++j) { asm("" : "+v"(bh[j]), "+v"(bl[j])); }

    __syncthreads();

    // ---- main loop: 16 tiles from LDS, DE-PHASED start per wave so matrix
    // and trans pipes overlap across waves instead of lockstep alternation.
    float p[TILES] = {0.f, 0.f, 0.f, 0.f};
    int ph = (wv << 1) & (CT - 1);               // per-wave tile phase offset
#pragma unroll 1
    for (int tt0 = 0; tt0 < CT; ++tt0) {
        int tt = (tt0 + ph) & (CT - 1);
        bf16x8 ah = *reinterpret_cast<const bf16x8*>(sm + ((size_t)tt * 64 + lane) * 8);
        bf16x8 al = *reinterpret_cast<const bf16x8*>(sm + 8192 + ((size_t)tt * 64 + lane) * 8);
#pragma unroll
        for (int j = 0; j < TILES; ++j) {
            f32x4 z = {0.f, 0.f, 0.f, 0.f};
            f32x4 acc = __builtin_amdgcn_mfma_f32_16x16x32_bf16(ah, bh[j], z, 0, 0, 0);
            acc = __builtin_amdgcn_mfma_f32_16x16x32_bf16(al, bh[j], acc, 0, 0, 0);
            acc = __builtin_amdgcn_mfma_f32_16x16x32_bf16(ah, bl[j], acc, 0, 0, 0);
            float e0 = __builtin_amdgcn_exp2f(acc[0]);
            float e1 = __builtin_amdgcn_exp2f(acc[1]);
            float e2 = __builtin_amdgcn_exp2f(acc[2]);
            float e3 = __builtin_amdgcn_exp2f(acc[3]);
            p[j] += (e0 + e1) + (e2 + e3);
        }
    }
    // reduce over the 4 q-quarters (column r fixed) and accumulate
#pragma unroll
    for (int j = 0; j < TILES; ++j) {
        p[j] += __shfl_xor(p[j], 16, 64);
        p[j] += __shfl_xor(p[j], 32, 64);
    }
    if (lane < 16) {
#pragma unroll
        for (int j = 0; j < TILES; ++j)
            atomicAdd(&out[m0 + j * 16 + r], p[j]);
    }
}

// ---- fallback: fp32 VALU kernel (no workspace needed)
constexpr int FTPB = 256;
constexpr int MPT  = 2;
constexpr int MBLK = FTPB * MPT;

__global__ __launch_bounds__(FTPB) void ke_plain(
    const float* __restrict__ x, const float* __restrict__ samples,
    const float* __restrict__ weights, const float* __restrict__ sigma_p,
    const float* __restrict__ length_p, float* __restrict__ out,
    int M, int N, int nsplit, int chunk) {
    int mb = blockIdx.x / nsplit;
    int ns = blockIdx.x - mb * nsplit;
    int t  = threadIdx.x;
    int m0 = mb * MBLK + t;
    int m1 = m0 + FTPB;
    int m0c = (m0 < M) ? m0 : 0;
    int m1c = (m1 < M) ? m1 : 0;

    v2f_ xaq[D / 2], xbq[D / 2];
    const v2f_* xp0 = reinterpret_cast<const v2f_*>(x + (size_t)m0c * D);
    const v2f_* xp1 = reinterpret_cast<const v2f_*>(x + (size_t)m1c * D);
#pragma unroll
    for (int qq = 0; qq < D / 2; ++qq) { xaq[qq] = xp0[qq]; xbq[qq] = xp1[qq]; }
#pragma unroll
    for (int qq = 0; qq < D / 2; ++qq) { asm("" : "+v"(xaq[qq])); asm("" : "+v"(xbq[qq])); }

    float l   = length_p[0];
    float c   = -0.5f * LOG2E_F / (l * l);
    float m2c = -2.f * c;
    float sg  = sigma_p[0];
    float sg2 = sg * sg;

    v2f_ qa = {0.f, 0.f}, qb = {0.f, 0.f};
#pragma unroll
    for (int qq = 0; qq < D / 2; ++qq) {
        qa = __builtin_elementwise_fma(xaq[qq], xaq[qq], qa);
        qb = __builtin_elementwise_fma(xbq[qq], xbq[qq], qb);
    }
    float cxa = c * (qa.x + qa.y);
    float cxb = c * (qb.x + qb.y);

    float acc0 = 0.f, acc1 = 0.f;
    int n0 = ns * chunk;
    int n1 = n0 + chunk;
    if (n1 > N) n1 = N;
#pragma unroll 2
    for (int n = n0; n < n1; ++n) {
        const v2f_* s2 = reinterpret_cast<const v2f_*>(samples + (size_t)n * D);
        v2f_ da = {0.f, 0.f}, db = {0.f, 0.f}, sq = {0.f, 0.f};
#pragma unroll
        for (int qq = 0; qq < D / 2; ++qq) {
            v2f_ sv = s2[qq];
            sq = __builtin_elementwise_fma(sv, sv, sq);
            da = __builtin_elementwise_fma(sv, xaq[qq], da);
            db = __builtin_elementwise_fma(sv, xbq[qq], db);
        }
        float cn = c * (sq.x + sq.y);
        float wn = sg2 * weights[n];
        float e0 = fmaf(m2c, da.x + da.y, cn);
        float e1 = fmaf(m2c, db.x + db.y, cn);
        acc0 = fmaf(wn, __builtin_amdgcn_exp2f(e0), acc0);
        acc1 = fmaf(wn, __builtin_amdgcn_exp2f(e1), acc1);
    }
    if (m0 < M) atomicAdd(&out[m0], acc0 * __builtin_amdgcn_exp2f(cxa));
    if (m1 < M) atomicAdd(&out[m1], acc1 * __builtin_amdgcn_exp2f(cxb));
}

extern "C" void kernel_launch(void* const* d_in, const int* in_sizes, int n_in,
                              void* d_out, int out_size, void* d_ws, size_t ws_size,
                              hipStream_t stream) {
    const float* x       = (const float*)d_in[0];
    const float* samples = (const float*)d_in[1];
    const float* weights = (const float*)d_in[2];
    const float* sigma_p = (const float*)d_in[3];
    const float* length_p= (const float*)d_in[4];
    float* out = (float*)d_out;

    int M = in_sizes[0] / D;
    int N = in_sizes[1] / D;

    hipMemsetAsync(out, 0, (size_t)out_size * sizeof(float), stream);

    int MSPAN = TILES * 16 * WB;                 // 512 m per block
    bool fused_ok = (M % MSPAN) == 0 && (N == NSPLIT * CT * 16) && out_size >= M;

    if (fused_ok) {
        int MGRP   = M / MSPAN;                  // 32
        int blocks = MGRP * NSPLIT;              // 1024 = exact device capacity
        ke_fused<<<dim3(blocks), dim3(TPB), 0, stream>>>(
            x, samples, weights, sigma_p, length_p, out, M, N, MGRP);
    } else {
        int mbcnt  = (M + MBLK - 1) / MBLK;
        int nsplit = 2048 / (mbcnt > 0 ? mbcnt : 1);
        if (nsplit < 1) nsplit = 1;
        if (nsplit > N) nsplit = N;
        int chunk = (N + nsplit - 1) / nsplit;
        ke_plain<<<dim3(mbcnt * nsplit), dim3(FTPB), 0, stream>>>(
            x, samples, weights, sigma_p, length_p, out, M, N, nsplit, chunk);
    }
}